// Round 4
// baseline (205.138 us; speedup 1.0000x reference)
//
#include <hip/hip_runtime.h>
#include <hip/hip_bf16.h>
#include <hip/hip_fp16.h>

// out[e] = relu(z_s[row[e]]@W1_top + z_c[col[e]]@W1_bot + b1) @ W2 + b2
// u_s = z_s@W1_top + b1 (f16), u_c = z_c@W1_bot (f16) in ws.
// Edges counting-sorted by row>>9 into XCD-grouped buckets so each XCD's L2
// serves a 128KB-hot u_s window; per edge: out = sum relu(us+uc)*W2 + b2.

typedef _Float16 half2v __attribute__((ext_vector_type(2)));
typedef _Float16 half8v __attribute__((ext_vector_type(8)));
typedef __fp16   fp16x2 __attribute__((ext_vector_type(2)));
typedef float    float4v __attribute__((ext_vector_type(4)));

#define NB 256          // sortkey space: 8 groups x 32 slots (keys 0..195 used)
#define EBLK 2048       // edges per hist/scatter block
#define B8 128          // edge blocks per XCD group

static __device__ __forceinline__ int sort_key(int r) {
    int key = r >> 9;                       // 0..195
    return (key & 7) * 32 + (key >> 3);     // group-major, <= 7*32+24 = 248
}

// ---- K1: W1 -> Wt[half][n][k] f16 (LDS transpose); W2 -> f16; zero hist ----
__global__ __launch_bounds__(256) void conv_w(const float* __restrict__ W1,
                                              const float* __restrict__ W2,
                                              _Float16* __restrict__ Wt,
                                              _Float16* __restrict__ w2h,
                                              unsigned* __restrict__ hist) {
    int b = blockIdx.x, t = threadIdx.x;
    if (b == 8) {
        if (t < 128) w2h[t] = (_Float16)W2[t];
        hist[t] = 0u;
        return;
    }
    __shared__ _Float16 lds[32][136];
    int h = b >> 2, n0 = (b & 3) * 32;
    for (int i = 0; i < 16; ++i) {
        int idx = i * 256 + t;              // 4096 = 128k x 32n
        int k = idx >> 5, nn = idx & 31;
        lds[nn][k] = (_Float16)W1[(h * 128 + k) * 128 + n0 + nn];
    }
    __syncthreads();
    for (int j = 0; j < 2; ++j) {
        int idx = j * 256 + t;              // 512 = 32n x 16 chunks
        int nn = idx >> 4, kc = idx & 15;
        half8v v;
        #pragma unroll
        for (int q = 0; q < 8; ++q) v[q] = lds[nn][kc * 8 + q];
        *(half8v*)&Wt[((h * 128 + n0 + nn) * 128) + kc * 8] = v;
    }
}

// ---- K2: global histogram of sort keys ----
__global__ __launch_bounds__(256) void hist_k(const int* __restrict__ row,
                                              unsigned* __restrict__ hist, int E) {
    __shared__ unsigned h[NB];
    int t = threadIdx.x;
    h[t] = 0;
    __syncthreads();
    int b0 = blockIdx.x * EBLK;
    #pragma unroll
    for (int i = 0; i < 8; ++i) {
        int e = b0 + i * 256 + t;
        if (e < E) atomicAdd(&h[sort_key(row[e])], 1u);
    }
    __syncthreads();
    if (h[t]) atomicAdd(&hist[t], h[t]);
}

// ---- K3: exclusive scan of 256 bins -> cursor bases + group starts ----
__global__ __launch_bounds__(256) void scan_k(const unsigned* __restrict__ hist,
                                              unsigned* __restrict__ cursor,
                                              unsigned* __restrict__ groupStart, int E) {
    __shared__ unsigned s[NB];
    int t = threadIdx.x;
    unsigned v = hist[t];
    s[t] = v;
    __syncthreads();
    for (int d = 1; d < NB; d <<= 1) {
        unsigned x = (t >= d) ? s[t - d] : 0u;
        __syncthreads();
        s[t] += x;
        __syncthreads();
    }
    unsigned excl = s[t] - v;
    cursor[t] = excl;
    if ((t & 31) == 0) groupStart[t >> 5] = excl;
    if (t == 0) groupStart[8] = (unsigned)E;
}

// ---- K4: scatter edges to permuted order (block-aggregated atomics) ----
__global__ __launch_bounds__(256) void scatter_k(const int* __restrict__ row,
                                                 const int* __restrict__ col,
                                                 unsigned* __restrict__ cursor,
                                                 uint2* __restrict__ perm, int E) {
    __shared__ unsigned h[NB];
    __shared__ unsigned base[NB];
    int t = threadIdx.x;
    h[t] = 0;
    __syncthreads();
    int b0 = blockIdx.x * EBLK;
    int sk[8], rr[8], cc[8];
    #pragma unroll
    for (int i = 0; i < 8; ++i) {
        int e = b0 + i * 256 + t;
        if (e < E) {
            rr[i] = row[e]; cc[i] = col[e];
            sk[i] = sort_key(rr[i]);
            atomicAdd(&h[sk[i]], 1u);
        } else sk[i] = -1;
    }
    __syncthreads();
    if (h[t]) base[t] = atomicAdd(&cursor[t], h[t]);
    __syncthreads();
    h[t] = 0;
    __syncthreads();
    #pragma unroll
    for (int i = 0; i < 8; ++i) {
        if (sk[i] >= 0) {
            unsigned off = atomicAdd(&h[sk[i]], 1u);
            unsigned pos = base[sk[i]] + off;
            int e = b0 + i * 256 + t;
            perm[pos] = make_uint2(((unsigned)rr[i] << 15) | (unsigned)cc[i], (unsigned)e);
        }
    }
}

// ---- K5: fused U_s / U_c GEMM, MFMA 16x16x32 f16 (unchanged from R3) ----
__global__ __launch_bounds__(256) void gemm_u(
    const float* __restrict__ Zs, const float* __restrict__ Zc,
    const _Float16* __restrict__ Wt, const float* __restrict__ b1,
    _Float16* __restrict__ Us, _Float16* __restrict__ Uc,
    int Ms, int Mc, int nbs)
{
    __shared__ uint4 ldsW[2048];            // 128 rows x 16 chunks, swizzled
    const int bid = blockIdx.x, t = threadIdx.x;

    const float* Z; _Float16* U; const _Float16* W; int M, m0, addB;
    if (bid < nbs) { Z = Zs; U = Us; M = Ms; m0 = bid * 64;         W = Wt;         addB = 1; }
    else           { Z = Zc; U = Uc; M = Mc; m0 = (bid - nbs) * 64; W = Wt + 16384; addB = 0; }

    const uint4* Wv = (const uint4*)W;
    #pragma unroll
    for (int i = 0; i < 8; ++i) {
        int j = i * 256 + t;
        int n = j >> 4, ch = j & 15;
        ldsW[n * 16 + (ch ^ ((n >> 3) & 7))] = Wv[j];
    }
    __syncthreads();

    const int wave = t >> 6, lane = t & 63, quad = lane >> 4, l16 = lane & 15;
    int mrow = m0 + wave * 16 + l16;
    int mload = mrow < M ? mrow : M - 1;
    const float* zrow = Z + (long)mload * 128;

    float4v acc[8];
    #pragma unroll
    for (int nt = 0; nt < 8; ++nt) acc[nt] = (float4v)(0.0f);

    #pragma unroll
    for (int c = 0; c < 4; ++c) {
        const float4v* pa = (const float4v*)(zrow + c * 32 + quad * 8);
        float4v a0 = pa[0], a1 = pa[1];
        fp16x2 p[4];
        p[0] = __builtin_amdgcn_cvt_pkrtz(a0[0], a0[1]);
        p[1] = __builtin_amdgcn_cvt_pkrtz(a0[2], a0[3]);
        p[2] = __builtin_amdgcn_cvt_pkrtz(a1[0], a1[1]);
        p[3] = __builtin_amdgcn_cvt_pkrtz(a1[2], a1[3]);
        half8v af;
        __builtin_memcpy(&af, &p[0], 16);
        const int ch = c * 4 + quad;
        #pragma unroll
        for (int nt = 0; nt < 8; ++nt) {
            const int n = l16 * 8 + nt;
            const half8v* pb = (const half8v*)&ldsW[n * 16 + (ch ^ (l16 & 7))];
            acc[nt] = __builtin_amdgcn_mfma_f32_16x16x32_f16(af, *pb, acc[nt], 0, 0, 0);
        }
    }

    float bv[8];
    if (addB) {
        const float4v* pb1 = (const float4v*)(b1 + l16 * 8);
        float4v x0 = pb1[0], x1 = pb1[1];
        bv[0]=x0[0]; bv[1]=x0[1]; bv[2]=x0[2]; bv[3]=x0[3];
        bv[4]=x1[0]; bv[5]=x1[1]; bv[6]=x1[2]; bv[7]=x1[3];
    } else {
        #pragma unroll
        for (int i = 0; i < 8; ++i) bv[i] = 0.0f;
    }

    const int rbase = m0 + wave * 16 + quad * 4;
    #pragma unroll
    for (int r = 0; r < 4; ++r) {
        int rr = rbase + r;
        if (rr < M) {
            half8v o;
            #pragma unroll
            for (int nt = 0; nt < 8; ++nt) o[nt] = (_Float16)(acc[nt][r] + bv[nt]);
            *(half8v*)&U[(long)rr * 128 + l16 * 8] = o;
        }
    }
}

// ---- K6: permuted edge gather + relu-dot; XCD-partitioned ----
__global__ __launch_bounds__(256) void edge_perm_k(
    const uint2* __restrict__ perm, const unsigned* __restrict__ groupStart,
    const _Float16* __restrict__ us, const _Float16* __restrict__ uc,
    const _Float16* __restrict__ w2h, const float* __restrict__ b2,
    float* __restrict__ out)
{
    const int t = threadIdx.x, sub = t & 7;
    const int g = blockIdx.x & 7;            // XCD group (blockIdx%8 -> XCD)
    const int j = blockIdx.x >> 3;
    unsigned s0 = groupStart[g], s1 = groupStart[g + 1];
    unsigned len = s1 - s0;
    unsigned chunk = (len + B8 - 1) / B8;
    unsigned lo = s0 + j * chunk;
    unsigned hi = lo + chunk; if (hi > s1) hi = s1;

    const uint4* pw = (const uint4*)(w2h + sub * 16);
    uint4 w0 = pw[0], w1 = pw[1];
    half2v W[8];
    *(uint4*)&W[0] = w0; *(uint4*)&W[4] = w1;
    const float b2v = b2[0];
    const half2v zero = {(_Float16)0, (_Float16)0};

    for (unsigned e = lo + (t >> 3); e < hi; e += 32) {
        uint2 pc = perm[e];
        unsigned rr = pc.x >> 15, cc = pc.x & 32767u;

        const uint4* pa = (const uint4*)(us + (long)rr * 128 + sub * 16);
        const uint4* pb = (const uint4*)(uc + (long)cc * 128 + sub * 16);
        uint4 a0 = pa[0], a1 = pa[1];
        uint4 c0 = pb[0], c1 = pb[1];

        half2v A[8], B[8];
        *(uint4*)&A[0] = a0; *(uint4*)&A[4] = a1;
        *(uint4*)&B[0] = c0; *(uint4*)&B[4] = c1;

        float s = 0.0f;
        #pragma unroll
        for (int i = 0; i < 8; ++i) {
            half2v h = A[i] + B[i];                   // v_pk_add_f16
            h = __builtin_elementwise_max(h, zero);   // v_pk_max_f16
            s += (float)h[0] * (float)W[i][0];
            s += (float)h[1] * (float)W[i][1];
        }
        s += __shfl_xor(s, 1);
        s += __shfl_xor(s, 2);
        s += __shfl_xor(s, 4);
        if (sub == 0) out[pc.y] = s + b2v;
    }
}

extern "C" void kernel_launch(void* const* d_in, const int* in_sizes, int n_in,
                              void* d_out, int out_size, void* d_ws, size_t ws_size,
                              hipStream_t stream) {
    const float* zs  = (const float*)d_in[0];
    const float* zc  = (const float*)d_in[1];
    const int*   row = (const int*)d_in[2];
    const int*   col = (const int*)d_in[3];
    const float* W1  = (const float*)d_in[4];
    const float* b1  = (const float*)d_in[5];
    const float* W2  = (const float*)d_in[6];
    const float* b2  = (const float*)d_in[7];
    float* out = (float*)d_out;

    const int Ms = in_sizes[0] / 128;   // 100000
    const int Mc = in_sizes[1] / 128;   // 20000
    const int E  = in_sizes[2];         // 1000000

    char* w = (char*)d_ws;
    _Float16* Wt      = (_Float16*)(w);                 // 65536 B
    _Float16* w2h     = (_Float16*)(w + 65536);         // 256 B
    unsigned* hist    = (unsigned*)(w + 66048);         // 1024 B
    unsigned* cursor  = (unsigned*)(w + 67072);         // 1024 B
    unsigned* gstart  = (unsigned*)(w + 68096);         // 64 B
    _Float16* us      = (_Float16*)(w + 131072);        // Ms*128*2 = 25,600,000 B
    _Float16* uc      = (_Float16*)(w + 131072 + (size_t)Ms * 256);      // Mc*128*2
    uint2*    perm    = (uint2*)(w + 131072 + (size_t)(Ms + Mc) * 256);  // E*8 B

    const int nbs = (Ms + 63) / 64, nbc = (Mc + 63) / 64;
    const int nbe = (E + EBLK - 1) / EBLK;              // 489

    conv_w   <<<9, 256, 0, stream>>>(W1, W2, Wt, w2h, hist);
    hist_k   <<<nbe, 256, 0, stream>>>(row, hist, E);
    scan_k   <<<1, 256, 0, stream>>>(hist, cursor, gstart, E);
    scatter_k<<<nbe, 256, 0, stream>>>(row, col, cursor, perm, E);
    gemm_u   <<<nbs + nbc, 256, 0, stream>>>(zs, zc, Wt, b1, us, uc, Ms, Mc, nbs);
    edge_perm_k<<<8 * B8, 256, 0, stream>>>(perm, gstart, us, uc, w2h, b2, out);
}